// Round 1
// baseline (272.631 us; speedup 1.0000x reference)
//
#include <hip/hip_runtime.h>
#include <math.h>

#define MAX_SLOTS 64
#define L 4096

// ws layout (bytes)
#define OFF_CNT   0
#define OFF_LIST  256
#define OFF_FSUB  16640          // 2*64*64*64*4 = 2097152
#define OFF_SF    2113792        // 2*MAX_SLOTS*4096*4 = 2097152
#define OFF_W     4210944        // 2097152

// ---------------- K0: mask -> active list ----------------
__global__ __launch_bounds__(256) void k_mask(const int* __restrict__ mask,
                                              int* __restrict__ cnt,
                                              int* __restrict__ list) {
    __shared__ int lcnt;
    if (threadIdx.x == 0) lcnt = 0;
    __syncthreads();
    for (int q = threadIdx.x; q < L; q += 256) {
        int qi = q >> 6, qj = q & 63;
        bool allz = true;
        for (int dy = -1; dy <= 1; ++dy)
            for (int dx = -1; dx <= 1; ++dx) {
                int y = qi + dy, x = qj + dx;
                if (y >= 0 && y < 64 && x >= 0 && x < 64)
                    allz = allz && (mask[y * 64 + x] == 0);
            }
        if (allz) { int p = atomicAdd(&lcnt, 1); list[p] = q; }
    }
    __syncthreads();
    if (threadIdx.x == 0) *cnt = lcnt;
}

// ---------------- K1: subsample f (= b) at stride 2 ----------------
__global__ __launch_bounds__(256) void k_fsub(const float* __restrict__ in,
                                              float* __restrict__ fsub) {
    int idx = blockIdx.x * 256 + threadIdx.x;      // 2*64*64*64 = 524288
    int j = idx & 63;
    int i = (idx >> 6) & 63;
    int c = (idx >> 12) & 63;
    int b = idx >> 18;
    fsub[idx] = in[(((b * 128 + c) * 128) + 2 * i) * 128 + 2 * j];
}

// ---------------- K2: fused correlation scores for active slots ----------------
// s_fused[q,P] = sum_{d1,d2 valid} <patch(Pterm), patch(R)> / max(||patch(R)||,eps)
// flat-index fuse semantics: X = tr(.)+d2 in [0,L); Z = untr(X)+d1 in [0,L)
__global__ __launch_bounds__(256) void k_scores(const float* __restrict__ fsub,
                                                const int* __restrict__ cnt,
                                                const int* __restrict__ list,
                                                float* __restrict__ sfused) {
    int slot = blockIdx.y;
    int nact = *cnt; if (nact > MAX_SLOTS) nact = MAX_SLOTS;
    if (slot >= nact) return;
    int b = blockIdx.z;
    int tx = threadIdx.x;               // 0..63  -> j
    int ty = threadIdx.y;               // 0..3
    int i = (blockIdx.x << 2) + ty;     // P row
    int j = tx;
    int tid = (ty << 6) + tx;           // 0..255
    int Q = list[slot];
    const float* F = fsub + (size_t)b * 262144;   // [c][y][x], 64*64*64

    __shared__ float patch[576];        // [c][3][3]
    __shared__ float red[256];
    __shared__ float s_inv;

    float s = 0.f;
    int P = (i << 6) + j;

    for (int d2 = -1; d2 <= 1; ++d2) {
        int XQ = ((Q & 63) << 6) + (Q >> 6) + d2;          // tr(Q)+d2
        if (XQ < 0 || XQ >= L) continue;                   // uniform
        int YQ = ((XQ & 63) << 6) + (XQ >> 6);             // untr
        int XP = ((P & 63) << 6) + (P >> 6) + d2;
        int YP = -1;
        if (XP >= 0 && XP < L) YP = ((XP & 63) << 6) + (XP >> 6);
        for (int d1 = -1; d1 <= 1; ++d1) {
            int R = YQ + d1;
            if (R < 0 || R >= L) continue;                 // uniform
            int ri = R >> 6, rj = R & 63;
            __syncthreads();
            // load normalized-patch source (raw) + partial sumsq
            float ss = 0.f;
            for (int t = tid; t < 576; t += 256) {
                int c = t / 9; int rem = t - c * 9;
                int dy = rem / 3 - 1; int dx = rem - (rem / 3) * 3 - 1;
                int y = ri + dy, x = rj + dx;
                float v = (y >= 0 && y < 64 && x >= 0 && x < 64)
                          ? F[(c << 12) + (y << 6) + x] : 0.f;
                patch[t] = v;
                ss += v * v;
            }
            red[tid] = ss;
            __syncthreads();
            if (tid < 64) {
                float a = red[tid] + red[tid + 64] + red[tid + 128] + red[tid + 192];
                for (int o = 32; o > 0; o >>= 1) a += __shfl_down(a, o);
                if (tid == 0) s_inv = 1.f / fmaxf(sqrtf(a), 1e-8f);
            }
            __syncthreads();
            // per-thread P-side term
            if (YP >= 0) {
                int Z = YP + d1;
                if (Z >= 0 && Z < L) {
                    int pi = Z >> 6, pj = Z & 63;
                    float dot = 0.f;
                    for (int dy = -1; dy <= 1; ++dy) {
                        int y = pi + dy; if (y < 0 || y >= 64) continue;
                        for (int dx = -1; dx <= 1; ++dx) {
                            int x = pj + dx; if (x < 0 || x >= 64) continue;
                            const float* fp = F + (y << 6) + x;
                            const float* pp = patch + (dy + 1) * 3 + (dx + 1);
                            #pragma unroll 16
                            for (int c = 0; c < 64; ++c)
                                dot += fp[(size_t)c << 12] * pp[c * 9];
                        }
                    }
                    s += dot * s_inv;
                }
            }
        }
    }
    sfused[((size_t)(b * MAX_SLOTS + slot) << 12) + P] = s;
}

// ---------------- K3: softmax over q (masked rows contribute exp(0)) ----------------
__global__ __launch_bounds__(256) void k_soft(const int* __restrict__ cnt,
                                              const float* __restrict__ sfused,
                                              float* __restrict__ wbuf) {
    int idx = blockIdx.x * 256 + threadIdx.x;   // 2*4096
    int b = idx >> 12; int P = idx & 4095;
    int nact = *cnt; if (nact > MAX_SLOTS) nact = MAX_SLOTS;
    float M = 0.f;   // masked rows have logit exactly 0 (nact < L always here)
    for (int s = 0; s < nact; ++s) {
        float l = 10.f * sfused[((size_t)(b * MAX_SLOTS + s) << 12) + P];
        M = fmaxf(M, l);
    }
    float denom = (float)(L - nact) * expf(-M);
    for (int s = 0; s < nact; ++s) {
        float e = expf(10.f * sfused[((size_t)(b * MAX_SLOTS + s) << 12) + P] - M);
        wbuf[((size_t)(b * MAX_SLOTS + s) << 12) + P] = e;
        denom += e;
    }
    float inv = 1.f / denom;
    for (int s = 0; s < nact; ++s)
        wbuf[((size_t)(b * MAX_SLOTS + s) << 12) + P] *= inv;
}

// ---------------- K4: aggregation + passthrough channels + concat ----------------
__global__ __launch_bounds__(128) void k_out(const float* __restrict__ in,
                                             const int* __restrict__ mask,
                                             const int* __restrict__ cnt,
                                             const int* __restrict__ list,
                                             const float* __restrict__ wbuf,
                                             float* __restrict__ out) {
    int v = threadIdx.x;          // 0..127
    int u = blockIdx.x;           // 0..127
    int c = blockIdx.y;           // 0..63
    int b = blockIdx.z;           // 0..1
    const float* inb = in + (size_t)((b * 128 + c) * 128) * 128;  // in[b][c][.][.]
    float val = inb[u * 128 + v];
    size_t ob = ((size_t)(b * 192) * 128 + (size_t)u) * 128 + v;  // channel stride 16384
    out[ob + (size_t)c * 16384] = val;            // b_full
    out[ob + (size_t)(c + 64) * 16384] = val;     // f_full
    float y = 0.f;
    if (mask[(u >> 1) * 64 + (v >> 1)] != 0) {
        int nact = *cnt; if (nact > MAX_SLOTS) nact = MAX_SLOTS;
        int pa = (u + 1) & 1;
        int pb = (v + 1) & 1;
        for (int s = 0; s < nact; ++s) {
            int q = list[s]; int qi = q >> 6, qj = q & 63;
            const float* wrow = wbuf + ((size_t)(b * MAX_SLOTS + s) << 12);
            for (int aa = pa; aa < 4; aa += 2) {
                int i = (u + 1 - aa) >> 1; if (i < 0 || i >= 64) continue;
                int row = 2 * qi - 1 + aa; if (row < 0 || row >= 128) continue;
                for (int bb = pb; bb < 4; bb += 2) {
                    int j = (v + 1 - bb) >> 1; if (j < 0 || j >= 64) continue;
                    int col = 2 * qj - 1 + bb; if (col < 0 || col >= 128) continue;
                    y += wrow[(i << 6) + j] * inb[row * 128 + col];
                }
            }
        }
        y *= 0.25f;
    }
    out[ob + (size_t)(c + 128) * 16384] = y;      // y
}

extern "C" void kernel_launch(void* const* d_in, const int* in_sizes, int n_in,
                              void* d_out, int out_size, void* d_ws, size_t ws_size,
                              hipStream_t stream) {
    const float* in = (const float*)d_in[0];
    const int* mask = (const int*)d_in[1];
    float* out = (float*)d_out;
    char* ws = (char*)d_ws;
    int* cnt    = (int*)(ws + OFF_CNT);
    int* list   = (int*)(ws + OFF_LIST);
    float* fsub = (float*)(ws + OFF_FSUB);
    float* sf   = (float*)(ws + OFF_SF);
    float* wbuf = (float*)(ws + OFF_W);

    k_mask<<<1, 256, 0, stream>>>(mask, cnt, list);
    k_fsub<<<2048, 256, 0, stream>>>(in, fsub);
    k_scores<<<dim3(16, MAX_SLOTS, 2), dim3(64, 4), 0, stream>>>(fsub, cnt, list, sf);
    k_soft<<<32, 256, 0, stream>>>(cnt, sf, wbuf);
    k_out<<<dim3(128, 64, 2), 128, 0, stream>>>(in, mask, cnt, list, wbuf, out);
}

// Round 2
// 187.031 us; speedup vs baseline: 1.4577x; 1.4577x over previous
//
#include <hip/hip_runtime.h>
#include <math.h>

#define MAX_SLOTS 64
#define L 4096

// ws layout (bytes)
#define OFF_CNT    0
#define OFF_LIST   64        // 64 ints
#define OFF_FLAGS  512       // 2*64*9*4 = 4608
#define OFF_PAT    5120      // 2*64*9*576*4 = 2654208
#define OFF_FSUB   2659328   // 2*64*66*66*4 = 2230272 (zero-padded border)
#define OFF_SF     4889600   // 2*64*4096*4 = 2097152
#define OFF_W      6986752   // 2097152
#define MEMSET_SZ  (2230272 + 2097152)   // fsub + sf contiguous

// ---------------- K0: mask -> active list ----------------
__global__ __launch_bounds__(256) void k_mask(const int* __restrict__ mask,
                                              int* __restrict__ cnt,
                                              int* __restrict__ list) {
    __shared__ int lcnt;
    if (threadIdx.x == 0) lcnt = 0;
    __syncthreads();
    for (int q = threadIdx.x; q < L; q += 256) {
        int qi = q >> 6, qj = q & 63;
        bool allz = true;
        for (int dy = -1; dy <= 1; ++dy)
            for (int dx = -1; dx <= 1; ++dx) {
                int y = qi + dy, x = qj + dx;
                if (y >= 0 && y < 64 && x >= 0 && x < 64)
                    allz = allz && (mask[y * 64 + x] == 0);
            }
        if (allz) {
            int p = atomicAdd(&lcnt, 1);
            if (p < MAX_SLOTS) list[p] = q;
        }
    }
    __syncthreads();
    if (threadIdx.x == 0) *cnt = (lcnt < MAX_SLOTS) ? lcnt : MAX_SLOTS;
}

// ---------------- K1: subsample f at stride 2 into zero-padded [c][66][66] ----------------
__global__ __launch_bounds__(256) void k_fsub(const float* __restrict__ in,
                                              float* __restrict__ fsub) {
    int idx = blockIdx.x * 256 + threadIdx.x;      // 2*64*64*64 = 524288
    int j = idx & 63;
    int i = (idx >> 6) & 63;
    int c = (idx >> 12) & 63;
    int b = idx >> 18;
    float v = in[(((b * 128 + c) * 128) + 2 * i) * 128 + 2 * j];
    fsub[(size_t)b * 278784 + c * 4356 + (i + 1) * 66 + (j + 1)] = v;
}

// ---------------- K2: normalized patch per (b, slot, combo), once ----------------
__global__ __launch_bounds__(64) void k_patch(const float* __restrict__ fsub,
                                              const int* __restrict__ cnt,
                                              const int* __restrict__ list,
                                              float* __restrict__ pat,
                                              int* __restrict__ flags) {
    int combo = blockIdx.x, slot = blockIdx.y, b = blockIdx.z;
    int fidx = (b * MAX_SLOTS + slot) * 9 + combo;
    int lane = threadIdx.x;
    int nact = min(*cnt, MAX_SLOTS);
    if (slot >= nact) { if (lane == 0) flags[fidx] = 0; return; }
    int d2 = combo / 3 - 1, d1 = combo % 3 - 1;
    int Q = list[slot];
    int XQ = ((Q & 63) << 6) + (Q >> 6) + d2;
    if (XQ < 0 || XQ >= L) { if (lane == 0) flags[fidx] = 0; return; }
    int YQ = ((XQ & 63) << 6) + (XQ >> 6);
    int R = YQ + d1;
    if (R < 0 || R >= L) { if (lane == 0) flags[fidx] = 0; return; }
    int ri = R >> 6, rj = R & 63;
    const float* F = fsub + (size_t)b * 278784;
    float vals[9]; float ss = 0.f;
    #pragma unroll
    for (int k = 0; k < 9; ++k) {
        int t = lane + (k << 6);               // covers 0..575
        int c = t / 9; int tap = t - c * 9;
        int dy = tap / 3 - 1, dx = tap - (tap / 3) * 3 - 1;
        float v = F[c * 4356 + (ri + dy + 1) * 66 + (rj + dx + 1)];
        vals[k] = v; ss += v * v;
    }
    for (int o = 32; o > 0; o >>= 1) ss += __shfl_xor(ss, o);
    float inv = 1.f / fmaxf(sqrtf(ss), 1e-8f);
    float* dst = pat + (size_t)fidx * 576;
    #pragma unroll
    for (int k = 0; k < 9; ++k) dst[lane + (k << 6)] = vals[k] * inv;
    if (lane == 0) flags[fidx] = 1;
}

// ---------------- K3: per-(slot,combo) correlation, atomic accumulate ----------------
__global__ __launch_bounds__(256) void k_scores2(const float* __restrict__ fsub,
                                                 const int* __restrict__ cnt,
                                                 const int* __restrict__ list,
                                                 const float* __restrict__ pat,
                                                 const int* __restrict__ flags,
                                                 float* __restrict__ sf) {
    int slot = blockIdx.y / 9;
    int combo = blockIdx.y - slot * 9;
    int b = blockIdx.z;
    int nact = min(*cnt, MAX_SLOTS);
    if (slot >= nact) return;
    int fidx = (b * MAX_SLOTS + slot) * 9 + combo;
    if (!flags[fidx]) return;
    int d2 = combo / 3 - 1, d1 = combo % 3 - 1;
    int P = blockIdx.x * 256 + threadIdx.x;
    int XP = ((P & 63) << 6) + (P >> 6) + d2;
    if (XP < 0 || XP >= L) return;
    int YP = ((XP & 63) << 6) + (XP >> 6);
    int Z = YP + d1;
    if (Z < 0 || Z >= L) return;
    int pi = Z >> 6, pj = Z & 63;
    const float* Fb = fsub + (size_t)b * 278784 + (pi + 1) * 66 + (pj + 1);
    const float* pp = pat + (size_t)fidx * 576;
    float a0 = 0.f, a1 = 0.f, a2 = 0.f;
    #pragma unroll 4
    for (int c = 0; c < 64; ++c) {
        const float* Fc = Fb + c * 4356;
        const float* pc = pp + c * 9;
        a0 += Fc[-67] * pc[0]; a1 += Fc[-66] * pc[1]; a2 += Fc[-65] * pc[2];
        a0 += Fc[-1]  * pc[3]; a1 += Fc[0]   * pc[4]; a2 += Fc[1]   * pc[5];
        a0 += Fc[65]  * pc[6]; a1 += Fc[66]  * pc[7]; a2 += Fc[67]  * pc[8];
    }
    atomicAdd(&sf[((size_t)(b * MAX_SLOTS + slot) << 12) + P], a0 + a1 + a2);
}

// ---------------- K4: softmax over slots (masked rows analytic) ----------------
__global__ __launch_bounds__(256) void k_soft(const int* __restrict__ cnt,
                                              const float* __restrict__ sf,
                                              float* __restrict__ wbuf) {
    int idx = blockIdx.x * 256 + threadIdx.x;   // 2*4096
    int b = idx >> 12; int P = idx & 4095;
    int nact = min(*cnt, MAX_SLOTS);
    float M = 0.f;   // masked rows have logit exactly 0
    for (int s = 0; s < nact; ++s) {
        float l = 10.f * sf[((size_t)(b * MAX_SLOTS + s) << 12) + P];
        M = fmaxf(M, l);
    }
    float denom = (float)(L - nact) * expf(-M);
    for (int s = 0; s < nact; ++s) {
        float e = expf(10.f * sf[((size_t)(b * MAX_SLOTS + s) << 12) + P] - M);
        wbuf[((size_t)(b * MAX_SLOTS + s) << 12) + P] = e;
        denom += e;
    }
    float inv = 1.f / denom;
    for (int s = 0; s < nact; ++s)
        wbuf[((size_t)(b * MAX_SLOTS + s) << 12) + P] *= inv;
}

// ---------------- K5: aggregation + passthrough, 4 channels/block, LDS patches ----------------
__global__ __launch_bounds__(128) void k_out(const float* __restrict__ in,
                                             const int* __restrict__ mask,
                                             const int* __restrict__ cnt,
                                             const int* __restrict__ list,
                                             const float* __restrict__ wbuf,
                                             float* __restrict__ out) {
    __shared__ float pat4[MAX_SLOTS * 64];   // [s][cc][16]: tap = aa*4+bb
    int u = blockIdx.x, cchunk = blockIdx.y, b = blockIdx.z;
    int tid = threadIdx.x;                   // v
    int nact = min(*cnt, MAX_SLOTS);
    const float* inb0 = in + (size_t)b * 2097152 + (size_t)(cchunk * 4) * 16384;
    for (int t = tid; t < nact * 64; t += 128) {
        int s = t >> 6; int r = t & 63;
        int cc = r >> 4; int e = r & 15; int aa = e >> 2; int bb = e & 3;
        int q = list[s]; int qi = q >> 6, qj = q & 63;
        int row = 2 * qi - 1 + aa, col = 2 * qj - 1 + bb;
        float v = (row >= 0 && row < 128 && col >= 0 && col < 128)
                  ? inb0[(size_t)cc * 16384 + row * 128 + col] : 0.f;
        pat4[t] = v;
    }
    __syncthreads();
    int v = tid;
    float y0 = 0.f, y1 = 0.f, y2 = 0.f, y3 = 0.f;
    if (mask[(u >> 1) * 64 + (v >> 1)] != 0) {
        int pa = (u + 1) & 1, pb = (v + 1) & 1;
        int i0 = (u + 1 - pa) >> 1, j0 = (v + 1 - pb) >> 1;
        for (int s = 0; s < nact; ++s) {
            const float* wrow = wbuf + ((size_t)(b * MAX_SLOTS + s) << 12);
            const float* ps = pat4 + s * 64;
            #pragma unroll
            for (int di = 0; di < 2; ++di) {
                int i = i0 - di; if (i < 0 || i >= 64) continue;
                int aa = pa + 2 * di;
                #pragma unroll
                for (int dj = 0; dj < 2; ++dj) {
                    int j = j0 - dj; if (j < 0 || j >= 64) continue;
                    float wv = wrow[(i << 6) + j];
                    int tap = aa * 4 + pb + 2 * dj;
                    y0 += wv * ps[tap];
                    y1 += wv * ps[16 + tap];
                    y2 += wv * ps[32 + tap];
                    y3 += wv * ps[48 + tap];
                }
            }
        }
        y0 *= 0.25f; y1 *= 0.25f; y2 *= 0.25f; y3 *= 0.25f;
    }
    size_t ob = (size_t)(b * 192) * 16384 + (size_t)u * 128 + v;
    float yv[4] = {y0, y1, y2, y3};
    #pragma unroll
    for (int cc = 0; cc < 4; ++cc) {
        int c = cchunk * 4 + cc;
        float val = in[(size_t)(b * 128 + c) * 16384 + u * 128 + v];
        out[ob + (size_t)c * 16384] = val;          // b_full
        out[ob + (size_t)(c + 64) * 16384] = val;   // f_full
        out[ob + (size_t)(c + 128) * 16384] = yv[cc]; // y
    }
}

extern "C" void kernel_launch(void* const* d_in, const int* in_sizes, int n_in,
                              void* d_out, int out_size, void* d_ws, size_t ws_size,
                              hipStream_t stream) {
    const float* in = (const float*)d_in[0];
    const int* mask = (const int*)d_in[1];
    float* out = (float*)d_out;
    char* ws = (char*)d_ws;
    int* cnt     = (int*)(ws + OFF_CNT);
    int* list    = (int*)(ws + OFF_LIST);
    int* flags   = (int*)(ws + OFF_FLAGS);
    float* pat   = (float*)(ws + OFF_PAT);
    float* fsub  = (float*)(ws + OFF_FSUB);
    float* sf    = (float*)(ws + OFF_SF);
    float* wbuf  = (float*)(ws + OFF_W);

    hipMemsetAsync(ws + OFF_FSUB, 0, MEMSET_SZ, stream);   // fsub padding + sf accumulator
    k_mask<<<1, 256, 0, stream>>>(mask, cnt, list);
    k_fsub<<<2048, 256, 0, stream>>>(in, fsub);
    k_patch<<<dim3(9, MAX_SLOTS, 2), 64, 0, stream>>>(fsub, cnt, list, pat, flags);
    k_scores2<<<dim3(16, MAX_SLOTS * 9, 2), 256, 0, stream>>>(fsub, cnt, list, pat, flags, sf);
    k_soft<<<32, 256, 0, stream>>>(cnt, sf, wbuf);
    k_out<<<dim3(128, 16, 2), 128, 0, stream>>>(in, mask, cnt, list, wbuf, out);
}